// Round 18
// baseline (251.107 us; speedup 1.0000x reference)
//
#include <hip/hip_runtime.h>
#include <hip/hip_bf16.h>
#include <math.h>

#define NN 4096
#define FF 512
#define CC 256
#define MAXD 128
#define JCH 512
#define NCH (NN / JCH)   // 8 column chunks
#define TAU_INV 1.25f    // 1/0.8
#define EPSF 1e-8f

#define NB_BUILD (2 * NN)                  // 8192 scan jobs
#define NB_L2N   NN                        // 4096 l2norm rows
#define NB_CAST  ((NN * FF) / (256 * 8))   // 1024 cast blocks (8 elem/thread)
#define NB_WT    (16 * 32 * 6)             // 3072 transpose tiles

typedef __attribute__((ext_vector_type(8))) short bf16x8;
typedef __attribute__((ext_vector_type(4))) float f32x4;

__device__ inline float b2f(short s) {
  return __uint_as_float(((unsigned)(unsigned short)s) << 16);
}

// ---------------- fat preamble: scan + l2norm + cast + transposes + zero ---
__global__ __launch_bounds__(256) void preamble(
    const float* __restrict__ A0, const float* __restrict__ A1,
    int* __restrict__ cntAll, int* __restrict__ idxAll, float* __restrict__ dinvAll,
    const float* __restrict__ z1, __hip_bfloat16* __restrict__ zn16,
    const float* __restrict__ x, __hip_bfloat16* __restrict__ x16,
    const float* __restrict__ Wg, const float* __restrict__ Wh,
    const float* __restrict__ W1h, const float* __restrict__ W1t,
    const float* __restrict__ W2h, const float* __restrict__ W2t,
    __hip_bfloat16* __restrict__ WT, __hip_bfloat16* __restrict__ W1T,
    __hip_bfloat16* __restrict__ W2T,
    float* __restrict__ csum8, float* __restrict__ outz) {
  __shared__ float smem[16 * 17];
  __shared__ int s_cnt;
  int bid = blockIdx.x;
  int t = threadIdx.x;

  if (bid < NB_BUILD) {
    int z = bid >> 12;
    int row = bid & (NN - 1);
    const float* A = z ? A1 : A0;
    int* idxz = idxAll + (size_t)z * NN * MAXD + row * MAXD;
    int wv = t >> 6, lane = t & 63;
    if (t == 0) s_cnt = 0;
    __syncthreads();
    const uint4* r = (const uint4*)(A + (size_t)row * NN);
    uint4 buf[4];
#pragma unroll
    for (int it = 0; it < 4; it++) buf[it] = r[(wv * 4 + it) * 64 + lane];
    int cnt_local = 0;
#pragma unroll
    for (int it = 0; it < 4; it++) {
      uint4 v = buf[it];
      cnt_local += __popcll(__ballot(v.x != 0u));
      cnt_local += __popcll(__ballot(v.y != 0u));
      cnt_local += __popcll(__ballot(v.z != 0u));
      cnt_local += __popcll(__ballot(v.w != 0u));
    }
    int woff = 0;
    if (lane == 0) woff = atomicAdd(&s_cnt, cnt_local);
    woff = __shfl(woff, 0, 64);
    unsigned long long pre = (1ull << lane) - 1;
    int off = woff;
#pragma unroll
    for (int it = 0; it < 4; it++) {
      uint4 v = buf[it];
      int col0 = ((wv * 4 + it) * 64 + lane) * 4;
      unsigned long long m0 = __ballot(v.x != 0u);
      unsigned long long m1 = __ballot(v.y != 0u);
      unsigned long long m2 = __ballot(v.z != 0u);
      unsigned long long m3 = __ballot(v.w != 0u);
      int o1 = off + __popcll(m0);
      int o2 = o1 + __popcll(m1);
      int o3 = o2 + __popcll(m2);
      if (v.x != 0u) {
        int p = off + __popcll(m0 & pre);
        if (p < MAXD) idxz[p] = col0;
      }
      if (v.y != 0u) {
        int p = o1 + __popcll(m1 & pre);
        if (p < MAXD) idxz[p] = col0 + 1;
      }
      if (v.z != 0u) {
        int p = o2 + __popcll(m2 & pre);
        if (p < MAXD) idxz[p] = col0 + 2;
      }
      if (v.w != 0u) {
        int p = o3 + __popcll(m3 & pre);
        if (p < MAXD) idxz[p] = col0 + 3;
      }
      off = o3 + __popcll(m3);
    }
    __syncthreads();
    if (t == 0) {
      int c = min(s_cnt, MAXD);
      cntAll[z * NN + row] = c;
      dinvAll[z * NN + row] = (c > 0) ? rsqrtf((float)c) : 0.f;
    }
    return;
  }
  bid -= NB_BUILD;

  if (bid < NB_L2N) {
    int i = bid;
    float v = z1[(size_t)i * CC + t];
    smem[t] = v * v;
    __syncthreads();
    for (int s = 128; s > 0; s >>= 1) {
      if (t < s) smem[t] += smem[t + s];
      __syncthreads();
    }
    float nrm = sqrtf(smem[0]) + EPSF;
    zn16[(size_t)i * CC + t] = __float2bfloat16(v / nrm);
    return;
  }
  bid -= NB_L2N;

  if (bid < NB_CAST) {
    int base = bid * 2048 + t * 8;
    float4 a = *(const float4*)(x + base);
    float4 b = *(const float4*)(x + base + 4);
    union {
      __hip_bfloat16 h[8];
      uint4 v;
    } u;
    u.h[0] = __float2bfloat16(a.x);
    u.h[1] = __float2bfloat16(a.y);
    u.h[2] = __float2bfloat16(a.z);
    u.h[3] = __float2bfloat16(a.w);
    u.h[4] = __float2bfloat16(b.x);
    u.h[5] = __float2bfloat16(b.y);
    u.h[6] = __float2bfloat16(b.z);
    u.h[7] = __float2bfloat16(b.w);
    *(uint4*)(x16 + base) = u.v;
    return;
  }
  bid -= NB_CAST;

  if (bid < NB_WT) {
    int z = bid / 512, rem = bid % 512;
    int bx = rem & 15, by = rem >> 4;
    const float* W;
    __hip_bfloat16* Wt;
    int K;
    if (z == 0)      { W = Wg;  Wt = WT;                     K = FF; }
    else if (z == 1) { W = Wh;  Wt = WT + (size_t)CC * FF;   K = FF; }
    else if (z == 2) { W = W1h; Wt = W1T;                    K = CC; }
    else if (z == 3) { W = W1t; Wt = W1T + (size_t)CC * CC;  K = CC; }
    else if (z == 4) { W = W2h; Wt = W2T;                    K = CC; }
    else             { W = W2t; Wt = W2T + (size_t)CC * CC;  K = CC; }
    int k0 = by * 16;
    if (k0 >= K) return;
    int j0 = bx * 16;
    float (*tile)[17] = (float(*)[17])smem;
    int tx = t & 15, ty = t >> 4;
    tile[ty][tx] = W[(size_t)(k0 + ty) * CC + j0 + tx];
    __syncthreads();
    Wt[(size_t)(j0 + ty) * K + k0 + tx] = __float2bfloat16(tile[tx][ty]);
    return;
  }
  bid -= NB_WT;

  for (int i = t; i < 8 * CC; i += 256) csum8[i] = 0.f;
  if (t == 0) *outz = 0.f;
}

// ---------------- CSR aggregation, both branches (z=2), bf16 ---------------
__global__ __launch_bounds__(256) void spmm_b16z(const int* __restrict__ cntAll,
                                                 const int* __restrict__ idxAll,
                                                 const float* __restrict__ dinvAll,
                                                 const __hip_bfloat162* __restrict__ Xb,
                                                 size_t xstride,
                                                 __hip_bfloat162* __restrict__ YbAll) {
  __shared__ int s_j[MAXD];
  __shared__ float s_w[MAXD];
  int z = blockIdx.z;
  const int* cnt = cntAll + z * NN;
  const int* idx = idxAll + (size_t)z * NN * MAXD;
  const float* dinv = dinvAll + z * NN;
  const __hip_bfloat162* X = Xb + z * xstride;
  __hip_bfloat162* Y = YbAll + (size_t)z * (NN * FF / 2);
  int i = blockIdx.x, t = threadIdx.x;
  int c = cnt[i];
  for (int e = t; e < c; e += 256) {
    int j = idx[i * MAXD + e];
    s_j[e] = j;
    s_w[e] = dinv[j];
  }
  __syncthreads();
  float ax = 0.f, ay = 0.f;
#pragma unroll 4
  for (int e = 0; e < c; e++) {
    int j = s_j[e];
    float w = s_w[e];
    __hip_bfloat162 v = X[(size_t)j * (FF / 2) + t];
    ax += w * __bfloat162float(v.x);
    ay += w * __bfloat162float(v.y);
  }
  float di = dinv[i];
  size_t base = (size_t)i * (FF / 2) + t;
  float ox, oy;
  if (z) {
    __hip_bfloat162 xi = X[base];
    ox = __bfloat162float(xi.x) - di * ax;
    oy = __bfloat162float(xi.y) - di * ay;
  } else {
    ox = di * ax;
    oy = di * ay;
  }
  __hip_bfloat162 o;
  o.x = __float2bfloat16(ox);
  o.y = __float2bfloat16(oy);
  Y[base] = o;
}

// ---------------- bf16 MFMA GEMM, both branches (z=2) ----------------------
template <int K, int RELU, int STATS, int L2OUT>
__global__ __launch_bounds__(256) void gemm_mfma2(const __hip_bfloat16* __restrict__ Aall,
                                                  const __hip_bfloat16* __restrict__ Btall,
                                                  const float* __restrict__ bias0,
                                                  const float* __restrict__ bias1,
                                                  float* __restrict__ Call,
                                                  __hip_bfloat16* __restrict__ Cball,
                                                  float* __restrict__ csumB) {
  __shared__ float rnorm[16];
  int z = blockIdx.z;
  const __hip_bfloat16* A = Aall + (size_t)z * NN * K;
  const __hip_bfloat16* Bt = Btall + (size_t)z * CC * K;
  const float* bias = z ? bias1 : bias0;
  float* csum = csumB ? csumB + z * 2 * CC : nullptr;
  float* csq = csum ? csum + CC : nullptr;
  int t = threadIdx.x;
  int lane = t & 63, wv = t >> 6;
  int l15 = lane & 15, lhi = lane >> 4;
  int row0 = blockIdx.x * 16;
  int col0 = wv * 64;
  if (L2OUT && t < 16) rnorm[t] = 0.f;
  const __hip_bfloat16* ap = A + (size_t)(row0 + l15) * K + lhi * 8;
  f32x4 acc[4] = {};
#pragma unroll
  for (int ks = 0; ks < K / 32; ks++) {
    bf16x8 a = *(const bf16x8*)(ap + ks * 32);
#pragma unroll
    for (int f = 0; f < 4; f++) {
      bf16x8 b = *(const bf16x8*)(Bt + (size_t)(col0 + f * 16 + l15) * K + ks * 32 + lhi * 8);
      acc[f] = __builtin_amdgcn_mfma_f32_16x16x32_bf16(a, b, acc[f], 0, 0, 0);
    }
  }
  float vout[4][4];
#pragma unroll
  for (int f = 0; f < 4; f++) {
    int col = col0 + f * 16 + l15;
    float bs = bias ? bias[col] : 0.f;
    float s = 0.f, q = 0.f;
#pragma unroll
    for (int reg = 0; reg < 4; reg++) {
      float v = acc[f][reg] + bs;
      if (RELU) v = fmaxf(v, 0.f);
      vout[f][reg] = v;
      if (STATS) {
        s += v;
        q += v * v;
      }
    }
    if (STATS) {
      s += __shfl_xor(s, 16, 64);
      s += __shfl_xor(s, 32, 64);
      q += __shfl_xor(q, 16, 64);
      q += __shfl_xor(q, 32, 64);
      if (lhi == 0) {
        atomicAdd(&csum[col], s);
        atomicAdd(&csq[col], q);
      }
    }
  }
  if (L2OUT) {
    __hip_bfloat16* Cb = Cball + (size_t)z * NN * CC;
    __syncthreads();
#pragma unroll
    for (int reg = 0; reg < 4; reg++) {
      float p = 0.f;
#pragma unroll
      for (int f = 0; f < 4; f++) p += vout[f][reg] * vout[f][reg];
#pragma unroll
      for (int m = 1; m <= 8; m <<= 1) p += __shfl_xor(p, m, 64);
      if (l15 == 0) atomicAdd(&rnorm[lhi * 4 + reg], p);
    }
    __syncthreads();
#pragma unroll
    for (int reg = 0; reg < 4; reg++) {
      float inv = 1.0f / (sqrtf(rnorm[lhi * 4 + reg]) + EPSF);
      int row = row0 + lhi * 4 + reg;
#pragma unroll
      for (int f = 0; f < 4; f++)
        Cb[(size_t)row * CC + col0 + f * 16 + l15] = __float2bfloat16(vout[f][reg] * inv);
    }
  } else {
    float* C = Call + (size_t)z * NN * CC;
#pragma unroll
    for (int reg = 0; reg < 4; reg++) {
      int row = row0 + lhi * 4 + reg;
#pragma unroll
      for (int f = 0; f < 4; f++)
        C[(size_t)row * CC + col0 + f * 16 + l15] = vout[f][reg];
    }
  }
}

// ---- fused BN-apply (no relu) + row l2norm, both branches (z=2) -----------
__global__ __launch_bounds__(256) void bn_l2z(const float* __restrict__ Hall,
                                              const float* __restrict__ csumB,
                                              const float* __restrict__ g,
                                              const float* __restrict__ b,
                                              __hip_bfloat16* __restrict__ HbAll,
                                              __hip_bfloat16* __restrict__ hnbAll) {
  __shared__ float red[256];
  int z = blockIdx.z;
  const float* X = Hall + (size_t)z * NN * CC;
  const float* csum = csumB + z * 2 * CC;
  const float* csq = csum + CC;
  __hip_bfloat16* Hb = HbAll + (size_t)z * NN * CC;
  __hip_bfloat16* hnb = hnbAll + (size_t)z * NN * CC;
  int i = blockIdx.x, t = threadIdx.x;
  float m = csum[t] / (float)NN;
  float var = csq[t] / (float)NN - m * m;
  float istd = 1.0f / sqrtf(var + 1e-5f);
  float v = g[t] * (X[(size_t)i * CC + t] - m) * istd + b[t];
  Hb[(size_t)i * CC + t] = __float2bfloat16(v);
  red[t] = v * v;
  __syncthreads();
  for (int s = 128; s > 0; s >>= 1) {
    if (t < s) red[t] += red[t + s];
    __syncthreads();
  }
  hnb[(size_t)i * CC + t] = __float2bfloat16(v / (sqrtf(red[0]) + EPSF));
}

// ---- BN-apply + relu, bf16 out, both branches (z=2), inline stats ---------
__global__ __launch_bounds__(256) void bn_applyz(const float* __restrict__ P1all,
                                                 const float* __restrict__ csumB,
                                                 const float* __restrict__ g0,
                                                 const float* __restrict__ g1,
                                                 const float* __restrict__ b0,
                                                 const float* __restrict__ b1,
                                                 __hip_bfloat16* __restrict__ Yall) {
  int z = blockIdx.z;
  const float* X = P1all + (size_t)z * NN * CC;
  const float* csum = csumB + z * 2 * CC;
  const float* csq = csum + CC;
  const float* g = z ? g1 : g0;
  const float* b = z ? b1 : b0;
  __hip_bfloat16* Y = Yall + (size_t)z * NN * CC;
  int idx = blockIdx.x * 256 + threadIdx.x;
  int c = idx & (CC - 1);
  float m = csum[c] / (float)NN;
  float var = csq[c] / (float)NN - m * m;
  float istd = 1.0f / sqrtf(var + 1e-5f);
  float v = g[c] * (X[idx] - m) * istd + b[c];
  v = fmaxf(v, 0.f);
  Y[idx] = __float2bfloat16(v);
}

// ---- fused: P1 gemm (blocks 0..255) + block-per-row topk (256..4351) ------
// topk: 16 groups of 16 lanes per block -> edges/pass 16 (was 4), serial
// passes ~4 (was ~16). Selection by wave 0, identical tie-break.
__global__ __launch_bounds__(256) void p1_and_topk(
    const __hip_bfloat16* __restrict__ HbAll, const __hip_bfloat16* __restrict__ W1T,
    const float* __restrict__ b1h, const float* __restrict__ b1t,
    float* __restrict__ P1all, float* __restrict__ csumP,
    const int* __restrict__ cntA, const int* __restrict__ idxA,
    const __hip_bfloat16* __restrict__ hnbAll, int* __restrict__ posidxAll) {
  __shared__ int s_j[MAXD];
  __shared__ float s_sim[MAXD];
  int z = blockIdx.z;
  int bx = blockIdx.x;
  int t = threadIdx.x;
  int lane = t & 63, wv = t >> 6;

  if (bx < NN / 16) {
    // ---- gemm role: P1[z] = Hb[z] @ W1[z]^T + b1[z], fused colstats ----
    const __hip_bfloat16* A = HbAll + (size_t)z * NN * CC;
    const __hip_bfloat16* Bt = W1T + (size_t)z * CC * CC;
    const float* bias = z ? b1t : b1h;
    float* csum = csumP + z * 2 * CC;
    float* csq = csum + CC;
    int l15 = lane & 15, lhi = lane >> 4;
    int row0 = bx * 16;
    int col0 = wv * 64;
    const __hip_bfloat16* ap = A + (size_t)(row0 + l15) * CC + lhi * 8;
    f32x4 acc[4] = {};
#pragma unroll
    for (int ks = 0; ks < CC / 32; ks++) {
      bf16x8 a = *(const bf16x8*)(ap + ks * 32);
#pragma unroll
      for (int f = 0; f < 4; f++) {
        bf16x8 b = *(const bf16x8*)(Bt + (size_t)(col0 + f * 16 + l15) * CC + ks * 32 + lhi * 8);
        acc[f] = __builtin_amdgcn_mfma_f32_16x16x32_bf16(a, b, acc[f], 0, 0, 0);
      }
    }
    float* C = P1all + (size_t)z * NN * CC;
#pragma unroll
    for (int f = 0; f < 4; f++) {
      int col = col0 + f * 16 + l15;
      float bs = bias[col];
      float s = 0.f, q = 0.f;
#pragma unroll
      for (int reg = 0; reg < 4; reg++) {
        float v = acc[f][reg] + bs;
        acc[f][reg] = v;
        s += v;
        q += v * v;
      }
      s += __shfl_xor(s, 16, 64);
      s += __shfl_xor(s, 32, 64);
      q += __shfl_xor(q, 16, 64);
      q += __shfl_xor(q, 32, 64);
      if (lhi == 0) {
        atomicAdd(&csum[col], s);
        atomicAdd(&csq[col], q);
      }
    }
#pragma unroll
    for (int reg = 0; reg < 4; reg++) {
      int row = row0 + lhi * 4 + reg;
#pragma unroll
      for (int f = 0; f < 4; f++)
        C[(size_t)row * CC + col0 + f * 16 + l15] = acc[f][reg];
    }
    return;
  }
  bx -= NN / 16;

  // ---- topk role: one block per row i = bx, 16 groups x 16 lanes ----
  const __hip_bfloat16* hnb = hnbAll + (size_t)z * NN * CC;
  int* posidx = posidxAll + (size_t)z * NN * 5;
  int grp = t >> 4, gl = t & 15;  // 16 groups of 16 consecutive lanes
  int i = bx;
  int c = cntA[i];
  const bf16x8* qrow = (const bf16x8*)(hnb + (size_t)i * CC);
  bf16x8 qa = qrow[gl], qb = qrow[16 + gl];
  float q0[8], q1[8];
#pragma unroll
  for (int d = 0; d < 8; d++) {
    q0[d] = b2f(qa[d]);
    q1[d] = b2f(qb[d]);
  }
  for (int e = t; e < c; e += 256) s_j[e] = idxA[i * MAXD + e];
  __syncthreads();
  int passes = (c + 15) >> 4;
  for (int p = 0; p < passes; p++) {
    int e = p * 16 + grp;
    bool val = e < c;
    int j = val ? s_j[e] : i;
    const bf16x8* hr = (const bf16x8*)(hnb + (size_t)j * CC);
    bf16x8 v0 = hr[gl];
    bf16x8 v1 = hr[16 + gl];
    float acc = 0.f;
#pragma unroll
    for (int d = 0; d < 8; d++) acc += q0[d] * b2f(v0[d]) + q1[d] * b2f(v1[d]);
#pragma unroll
    for (int m = 1; m <= 8; m <<= 1) acc += __shfl_xor(acc, m, 64);
    if (gl == 0 && val) s_sim[e] = acc;
  }
  __syncthreads();
  if (wv == 0) {
    float sim[2];
    int jj[2];
#pragma unroll
    for (int r = 0; r < 2; r++) {
      int e = lane + r * 64;
      bool v = e < c;
      sim[r] = v ? s_sim[e] : -1e30f;
      jj[r] = v ? s_j[e] : NN;
    }
    for (int k = 0; k < 5; k++) {
      float bv;
      int bj, br;
      if (sim[0] > sim[1] || (sim[0] == sim[1] && jj[0] < jj[1])) {
        bv = sim[0]; bj = jj[0]; br = 0;
      } else {
        bv = sim[1]; bj = jj[1]; br = 1;
      }
      float rv = bv;
      int rj = bj;
#pragma unroll
      for (int m = 1; m < 64; m <<= 1) {
        float ov = __shfl_xor(rv, m, 64);
        int oj = __shfl_xor(rj, m, 64);
        if (ov > rv || (ov == rv && oj < rj)) {
          rv = ov;
          rj = oj;
        }
      }
      if (lane == 0) posidx[i * 5 + k] = (rv > -1e29f) ? rj : -1;
      if (bj == rj && bv == rv && rv > -1e29f) {
        sim[br] = -1e30f;
        jj[br] = NN;
      }
    }
  }
}

// ---------------- fused contrast, global_load_lds-staged B -----------------
__global__ __launch_bounds__(256) void contrast_mfmaz(const __hip_bfloat16* __restrict__ zn,
                                                      const __hip_bfloat16* __restrict__ hpnAll,
                                                      const int* __restrict__ posidxAll,
                                                      float* __restrict__ part_rs,
                                                      float* __restrict__ part_pm) {
  __shared__ unsigned lmask[64 * (JCH / 32)];
  __shared__ float lds_rs[64], lds_pm[64];
  __shared__ unsigned char ldsB[64 * 512];
  int t = threadIdx.x;
  int br = blockIdx.z;
  const __hip_bfloat16* hpn = hpnAll + (size_t)br * NN * CC;
  const int* posidx = posidxAll + (size_t)br * NN * 5;
  int bi = blockIdx.y * 64;
  int bj0 = blockIdx.x * JCH;
  for (int w = t; w < 64 * (JCH / 32); w += 256) lmask[w] = 0;
  if (t < 64) {
    lds_rs[t] = 0.f;
    lds_pm[t] = 0.f;
  }
  __syncthreads();
  for (int p = t; p < 64 * 5; p += 256) {
    int gj = posidx[(bi + p / 5) * 5 + (p % 5)];
    int loc = gj - bj0;
    if (loc >= 0 && loc < JCH)
      atomicOr(&lmask[(p / 5) * (JCH / 32) + (loc >> 5)], 1u << (loc & 31));
  }
  if (t < 64) {
    int loc = bi + t - bj0;
    if (loc >= 0 && loc < JCH)
      atomicOr(&lmask[t * (JCH / 32) + (loc >> 5)], 1u << (loc & 31));
  }
  int lane = t & 63, wv = t >> 6;
  int wi = wv >> 1, wj = wv & 1;
  int l15 = lane & 15, lhi = lane >> 4;
  bf16x8 afrag[2][8];
#pragma unroll
  for (int fi = 0; fi < 2; fi++) {
    const __hip_bfloat16* ap = zn + (size_t)(bi + wi * 32 + fi * 16 + l15) * CC + lhi * 8;
#pragma unroll
    for (int ks = 0; ks < 8; ks++) afrag[fi][ks] = *(const bf16x8*)(ap + ks * 32);
  }
  float rs_acc[2][4] = {}, pm_acc[2][4] = {};
  int rb0 = wj * 32 + l15;
  int rb1 = rb0 + 16;
  int sw = rb0 & 7;
  int row_l = lane >> 5;
  int c16p = lane & 31;
  __syncthreads();
  for (int jt = 0; jt < JCH / 64; jt++) {
    __syncthreads();
#pragma unroll
    for (int it = 0; it < 8; it++) {
      int r = wv * 16 + it * 2 + row_l;
      const __hip_bfloat16* src =
          hpn + (size_t)(bj0 + jt * 64 + r) * CC + ((c16p ^ (r & 7)) << 3);
      __builtin_amdgcn_global_load_lds(
          (const __attribute__((address_space(1))) void*)src,
          (__attribute__((address_space(3))) void*)(ldsB + wv * 8192 + it * 1024),
          16, 0, 0);
    }
    __syncthreads();
    f32x4 acc[2][2] = {};
#pragma unroll
    for (int ks = 0; ks < 8; ks++) {
      int s16 = (ks << 2) + lhi;
      bf16x8 b0 = *(const bf16x8*)(ldsB + rb0 * 512 + ((s16 ^ sw) << 4));
      bf16x8 b1 = *(const bf16x8*)(ldsB + rb1 * 512 + ((s16 ^ sw) << 4));
      acc[0][0] = __builtin_amdgcn_mfma_f32_16x16x32_bf16(afrag[0][ks], b0, acc[0][0], 0, 0, 0);
      acc[1][0] = __builtin_amdgcn_mfma_f32_16x16x32_bf16(afrag[1][ks], b0, acc[1][0], 0, 0, 0);
      acc[0][1] = __builtin_amdgcn_mfma_f32_16x16x32_bf16(afrag[0][ks], b1, acc[0][1], 0, 0, 0);
      acc[1][1] = __builtin_amdgcn_mfma_f32_16x16x32_bf16(afrag[1][ks], b1, acc[1][1], 0, 0, 0);
    }
#pragma unroll
    for (int fi = 0; fi < 2; fi++) {
#pragma unroll
      for (int reg = 0; reg < 4; reg++) {
        int rloc = wi * 32 + fi * 16 + lhi * 4 + reg;
        unsigned word = lmask[rloc * (JCH / 32) + jt * 2 + wj];
#pragma unroll
        for (int fj = 0; fj < 2; fj++) {
          float e = __expf(acc[fi][fj][reg] * TAU_INV);
          rs_acc[fi][reg] += e;
          if ((word >> (fj * 16 + l15)) & 1) pm_acc[fi][reg] += e;
        }
      }
    }
  }
#pragma unroll
  for (int fi = 0; fi < 2; fi++) {
#pragma unroll
    for (int reg = 0; reg < 4; reg++) {
      float rs = rs_acc[fi][reg], pm = pm_acc[fi][reg];
#pragma unroll
      for (int m = 8; m >= 1; m >>= 1) {
        rs += __shfl_xor(rs, m, 64);
        pm += __shfl_xor(pm, m, 64);
      }
      if (l15 == 0) {
        int rloc = wi * 32 + fi * 16 + lhi * 4 + reg;
        atomicAdd(&lds_rs[rloc], rs);
        atomicAdd(&lds_pm[rloc], pm);
      }
    }
  }
  __syncthreads();
  if (t < 64) {
    size_t po = ((size_t)br * NCH + blockIdx.x) * NN + bi + t;
    part_rs[po] = lds_rs[t];
    part_pm[po] = lds_pm[t];
  }
}

// ---------------- final loss over both branches' chunk partials ------------
__global__ __launch_bounds__(256) void loss_reduce3(const float* __restrict__ part_rs,
                                                    const float* __restrict__ part_pm,
                                                    float* __restrict__ out) {
  __shared__ float red[256];
  int t = threadIdx.x;
  float s = 0.f;
  for (int i = blockIdx.x * 256 + t; i < NN; i += gridDim.x * 256) {
#pragma unroll
    for (int b = 0; b < 2; b++) {
      float rs = 0.f, pm = 0.f;
#pragma unroll
      for (int c = 0; c < NCH; c++) {
        rs += part_rs[((size_t)b * NCH + c) * NN + i];
        pm += part_pm[((size_t)b * NCH + c) * NN + i];
      }
      float sn = pm / (rs + EPSF);
      s += -logf(sn + EPSF);
    }
  }
  red[t] = s;
  __syncthreads();
  for (int k = 128; k > 0; k >>= 1) {
    if (t < k) red[t] += red[t + k];
    __syncthreads();
  }
  if (t == 0) atomicAdd(out, red[0] / (float)NN);
}

extern "C" void kernel_launch(void* const* d_in, const int* in_sizes, int n_in,
                              void* d_out, int out_size, void* d_ws, size_t ws_size,
                              hipStream_t stream) {
  const float* x = (const float*)d_in[0];
  const float* z1 = (const float*)d_in[1];
  const float* adj = (const float*)d_in[2];
  const float* adj2 = (const float*)d_in[3];
  const float* W_gcn = (const float*)d_in[4];
  const float* W_het = (const float*)d_in[5];
  const float* hpW1 = (const float*)d_in[6];
  const float* hpb1 = (const float*)d_in[7];
  const float* hpg = (const float*)d_in[8];
  const float* hpbe = (const float*)d_in[9];
  const float* hpW2 = (const float*)d_in[10];
  const float* hpb2 = (const float*)d_in[11];
  const float* tpW1 = (const float*)d_in[12];
  const float* tpb1 = (const float*)d_in[13];
  const float* tpg = (const float*)d_in[14];
  const float* tpbe = (const float*)d_in[15];
  const float* tpW2 = (const float*)d_in[16];
  const float* tpb2 = (const float*)d_in[17];
  const float* bng = (const float*)d_in[18];
  const float* bnb = (const float*)d_in[19];
  float* out = (float*)d_out;

  float* ws = (float*)d_ws;
  size_t oZN   = 0;
  size_t oX16  = oZN + (size_t)NN * CC / 2;
  size_t oB1B  = oX16 + (size_t)NN * FF / 2;
  size_t oB2B  = oB1B + (size_t)NN * FF;
  size_t oH    = oB2B + (size_t)NN * FF;
  size_t oHB   = oH + (size_t)2 * NN * CC;
  size_t oHNB  = oHB + (size_t)NN * CC;
  size_t oP1   = oHNB + (size_t)NN * CC;
  size_t oP1B  = oP1 + (size_t)2 * NN * CC;
  size_t oPN   = oP1B + (size_t)NN * CC;
  size_t oIDX  = oPN + (size_t)NN * CC;
  size_t oCNT  = oIDX + (size_t)2 * NN * MAXD;
  size_t oDI   = oCNT + 2 * NN;
  size_t oCS   = oDI + 2 * NN;
  size_t oPI   = oCS + 8 * CC;
  size_t oPR   = oPI + 2 * NN * 5;
  size_t oPP   = oPR + (size_t)2 * NCH * NN;
  size_t oWT   = oPP + (size_t)2 * NCH * NN;
  size_t oW1T  = oWT + (size_t)CC * FF;
  size_t oW2T  = oW1T + (size_t)CC * CC;

  __hip_bfloat16* zn16 = (__hip_bfloat16*)(ws + oZN);
  __hip_bfloat162* x16 = (__hip_bfloat162*)(ws + oX16);
  __hip_bfloat162* buf1b = (__hip_bfloat162*)(ws + oB1B);
  __hip_bfloat162* buf2b = (__hip_bfloat162*)(ws + oB2B);
  float* Hall = ws + oH;
  __hip_bfloat16* HbAll = (__hip_bfloat16*)(ws + oHB);
  __hip_bfloat16* hnbAll = (__hip_bfloat16*)(ws + oHNB);
  float* P1all = ws + oP1;
  __hip_bfloat16* P1bAll = (__hip_bfloat16*)(ws + oP1B);
  __hip_bfloat16* hpnAll = (__hip_bfloat16*)(ws + oPN);
  int* idxAll = (int*)(ws + oIDX);
  int* cntAll = (int*)(ws + oCNT);
  float* dinvAll = ws + oDI;
  float* csumH = ws + oCS;            // [2][2*CC]
  float* csumP = csumH + 4 * CC;      // [2][2*CC]
  int* posidxAll = (int*)(ws + oPI);
  float* part_rs = ws + oPR;
  float* part_pm = ws + oPP;
  __hip_bfloat16* WT = (__hip_bfloat16*)(ws + oWT);
  __hip_bfloat16* W1T = (__hip_bfloat16*)(ws + oW1T);
  __hip_bfloat16* W2T = (__hip_bfloat16*)(ws + oW2T);

  preamble<<<NB_BUILD + NB_L2N + NB_CAST + NB_WT + 1, 256, 0, stream>>>(
      adj, adj2, cntAll, idxAll, dinvAll, z1, zn16, x, (__hip_bfloat16*)x16,
      W_gcn, W_het, hpW1, tpW1, hpW2, tpW2, WT, W1T, W2T, csumH, out);

  spmm_b16z<<<dim3(NN, 1, 2), 256, 0, stream>>>(cntAll, idxAll, dinvAll, x16, 0, buf1b);
  spmm_b16z<<<dim3(NN, 1, 2), 256, 0, stream>>>(cntAll, idxAll, dinvAll, buf1b,
                                                (size_t)NN * FF / 2, buf2b);
  gemm_mfma2<FF, 1, 1, 0><<<dim3(NN / 16, 1, 2), 256, 0, stream>>>(
      (const __hip_bfloat16*)buf2b, WT, nullptr, nullptr, Hall, nullptr, csumH);
  bn_l2z<<<dim3(NN, 1, 2), 256, 0, stream>>>(Hall, csumH, bng, bnb, HbAll, hnbAll);
  p1_and_topk<<<dim3(NN / 16 + NN, 1, 2), 256, 0, stream>>>(
      HbAll, W1T, hpb1, tpb1, P1all, csumP, cntAll, idxAll, hnbAll, posidxAll);
  bn_applyz<<<dim3((NN * CC) / 256, 1, 2), 256, 0, stream>>>(P1all, csumP, hpg, tpg,
                                                             hpbe, tpbe, P1bAll);
  gemm_mfma2<CC, 0, 0, 1><<<dim3(NN / 16, 1, 2), 256, 0, stream>>>(
      P1bAll, W2T, hpb2, tpb2, nullptr, hpnAll, nullptr);
  contrast_mfmaz<<<dim3(NCH, NN / 64, 2), 256, 0, stream>>>(zn16, hpnAll, posidxAll,
                                                            part_rs, part_pm);
  loss_reduce3<<<16, 256, 0, stream>>>(part_rs, part_pm, out);
  (void)in_sizes; (void)n_in; (void)out_size; (void)ws_size;
}

// Round 19
// 240.305 us; speedup vs baseline: 1.0450x; 1.0450x over previous
//
#include <hip/hip_runtime.h>
#include <hip/hip_bf16.h>
#include <math.h>

#define NN 4096
#define FF 512
#define CC 256
#define MAXD 128
#define JCH 512
#define NCH (NN / JCH)   // 8 column chunks
#define TAU_INV 1.25f    // 1/0.8
#define EPSF 1e-8f

#define NB_BUILD (2 * NN)
#define NB_L2N   NN
#define NB_CAST  ((NN * FF) / (256 * 8))
#define NB_WT    (16 * 32 * 6)

typedef __attribute__((ext_vector_type(8))) short bf16x8;
typedef __attribute__((ext_vector_type(4))) float f32x4;

__device__ inline float b2f(short s) {
  return __uint_as_float(((unsigned)(unsigned short)s) << 16);
}
__device__ inline short f2b(float v) {
  __hip_bfloat16 h = __float2bfloat16(v);
  return *reinterpret_cast<short*>(&h);
}

// ---------------- fat preamble: scan + l2norm + cast + transposes + zero ---
__global__ __launch_bounds__(256) void preamble(
    const float* __restrict__ A0, const float* __restrict__ A1,
    int* __restrict__ cntAll, int* __restrict__ idxAll, float* __restrict__ dinvAll,
    const float* __restrict__ z1, __hip_bfloat16* __restrict__ zn16,
    const float* __restrict__ x, __hip_bfloat16* __restrict__ x16,
    const float* __restrict__ Wg, const float* __restrict__ Wh,
    const float* __restrict__ W1h, const float* __restrict__ W1t,
    const float* __restrict__ W2h, const float* __restrict__ W2t,
    __hip_bfloat16* __restrict__ WT, __hip_bfloat16* __restrict__ W1T,
    __hip_bfloat16* __restrict__ W2T,
    float* __restrict__ csum8, float* __restrict__ outz) {
  __shared__ float smem[16 * 17];
  __shared__ int s_cnt;
  int bid = blockIdx.x;
  int t = threadIdx.x;

  if (bid < NB_BUILD) {
    int z = bid >> 12;
    int row = bid & (NN - 1);
    const float* A = z ? A1 : A0;
    int* idxz = idxAll + (size_t)z * NN * MAXD + row * MAXD;
    int wv = t >> 6, lane = t & 63;
    if (t == 0) s_cnt = 0;
    __syncthreads();
    const uint4* r = (const uint4*)(A + (size_t)row * NN);
    uint4 buf[4];
#pragma unroll
    for (int it = 0; it < 4; it++) buf[it] = r[(wv * 4 + it) * 64 + lane];
    int cnt_local = 0;
#pragma unroll
    for (int it = 0; it < 4; it++) {
      uint4 v = buf[it];
      cnt_local += __popcll(__ballot(v.x != 0u));
      cnt_local += __popcll(__ballot(v.y != 0u));
      cnt_local += __popcll(__ballot(v.z != 0u));
      cnt_local += __popcll(__ballot(v.w != 0u));
    }
    int woff = 0;
    if (lane == 0) woff = atomicAdd(&s_cnt, cnt_local);
    woff = __shfl(woff, 0, 64);
    unsigned long long pre = (1ull << lane) - 1;
    int off = woff;
#pragma unroll
    for (int it = 0; it < 4; it++) {
      uint4 v = buf[it];
      int col0 = ((wv * 4 + it) * 64 + lane) * 4;
      unsigned long long m0 = __ballot(v.x != 0u);
      unsigned long long m1 = __ballot(v.y != 0u);
      unsigned long long m2 = __ballot(v.z != 0u);
      unsigned long long m3 = __ballot(v.w != 0u);
      int o1 = off + __popcll(m0);
      int o2 = o1 + __popcll(m1);
      int o3 = o2 + __popcll(m2);
      if (v.x != 0u) {
        int p = off + __popcll(m0 & pre);
        if (p < MAXD) idxz[p] = col0;
      }
      if (v.y != 0u) {
        int p = o1 + __popcll(m1 & pre);
        if (p < MAXD) idxz[p] = col0 + 1;
      }
      if (v.z != 0u) {
        int p = o2 + __popcll(m2 & pre);
        if (p < MAXD) idxz[p] = col0 + 2;
      }
      if (v.w != 0u) {
        int p = o3 + __popcll(m3 & pre);
        if (p < MAXD) idxz[p] = col0 + 3;
      }
      off = o3 + __popcll(m3);
    }
    __syncthreads();
    if (t == 0) {
      int c = min(s_cnt, MAXD);
      cntAll[z * NN + row] = c;
      dinvAll[z * NN + row] = (c > 0) ? rsqrtf((float)c) : 0.f;
    }
    return;
  }
  bid -= NB_BUILD;

  if (bid < NB_L2N) {
    int i = bid;
    float v = z1[(size_t)i * CC + t];
    smem[t] = v * v;
    __syncthreads();
    for (int s = 128; s > 0; s >>= 1) {
      if (t < s) smem[t] += smem[t + s];
      __syncthreads();
    }
    float nrm = sqrtf(smem[0]) + EPSF;
    zn16[(size_t)i * CC + t] = __float2bfloat16(v / nrm);
    return;
  }
  bid -= NB_L2N;

  if (bid < NB_CAST) {
    int base = bid * 2048 + t * 8;
    float4 a = *(const float4*)(x + base);
    float4 b = *(const float4*)(x + base + 4);
    union {
      __hip_bfloat16 h[8];
      uint4 v;
    } u;
    u.h[0] = __float2bfloat16(a.x);
    u.h[1] = __float2bfloat16(a.y);
    u.h[2] = __float2bfloat16(a.z);
    u.h[3] = __float2bfloat16(a.w);
    u.h[4] = __float2bfloat16(b.x);
    u.h[5] = __float2bfloat16(b.y);
    u.h[6] = __float2bfloat16(b.z);
    u.h[7] = __float2bfloat16(b.w);
    *(uint4*)(x16 + base) = u.v;
    return;
  }
  bid -= NB_CAST;

  if (bid < NB_WT) {
    int z = bid / 512, rem = bid % 512;
    int bx = rem & 15, by = rem >> 4;
    const float* W;
    __hip_bfloat16* Wt;
    int K;
    if (z == 0)      { W = Wg;  Wt = WT;                     K = FF; }
    else if (z == 1) { W = Wh;  Wt = WT + (size_t)CC * FF;   K = FF; }
    else if (z == 2) { W = W1h; Wt = W1T;                    K = CC; }
    else if (z == 3) { W = W1t; Wt = W1T + (size_t)CC * CC;  K = CC; }
    else if (z == 4) { W = W2h; Wt = W2T;                    K = CC; }
    else             { W = W2t; Wt = W2T + (size_t)CC * CC;  K = CC; }
    int k0 = by * 16;
    if (k0 >= K) return;
    int j0 = bx * 16;
    float (*tile)[17] = (float(*)[17])smem;
    int tx = t & 15, ty = t >> 4;
    tile[ty][tx] = W[(size_t)(k0 + ty) * CC + j0 + tx];
    __syncthreads();
    Wt[(size_t)(j0 + ty) * K + k0 + tx] = __float2bfloat16(tile[tx][ty]);
    return;
  }
  bid -= NB_WT;

  for (int i = t; i < 8 * CC; i += 256) csum8[i] = 0.f;
  if (t == 0) *outz = 0.f;
}

// ---------------- CSR aggregation, both branches (z=2), bf16 ---------------
__global__ __launch_bounds__(256) void spmm_b16z(const int* __restrict__ cntAll,
                                                 const int* __restrict__ idxAll,
                                                 const float* __restrict__ dinvAll,
                                                 const __hip_bfloat162* __restrict__ Xb,
                                                 size_t xstride,
                                                 __hip_bfloat162* __restrict__ YbAll) {
  __shared__ int s_j[MAXD];
  __shared__ float s_w[MAXD];
  int z = blockIdx.z;
  const int* cnt = cntAll + z * NN;
  const int* idx = idxAll + (size_t)z * NN * MAXD;
  const float* dinv = dinvAll + z * NN;
  const __hip_bfloat162* X = Xb + z * xstride;
  __hip_bfloat162* Y = YbAll + (size_t)z * (NN * FF / 2);
  int i = blockIdx.x, t = threadIdx.x;
  int c = cnt[i];
  for (int e = t; e < c; e += 256) {
    int j = idx[i * MAXD + e];
    s_j[e] = j;
    s_w[e] = dinv[j];
  }
  __syncthreads();
  float ax = 0.f, ay = 0.f;
#pragma unroll 4
  for (int e = 0; e < c; e++) {
    int j = s_j[e];
    float w = s_w[e];
    __hip_bfloat162 v = X[(size_t)j * (FF / 2) + t];
    ax += w * __bfloat162float(v.x);
    ay += w * __bfloat162float(v.y);
  }
  float di = dinv[i];
  size_t base = (size_t)i * (FF / 2) + t;
  float ox, oy;
  if (z) {
    __hip_bfloat162 xi = X[base];
    ox = __bfloat162float(xi.x) - di * ax;
    oy = __bfloat162float(xi.y) - di * ay;
  } else {
    ox = di * ax;
    oy = di * ay;
  }
  __hip_bfloat162 o;
  o.x = __float2bfloat16(ox);
  o.y = __float2bfloat16(oy);
  Y[base] = o;
}

// ---------------- bf16 MFMA GEMM, both branches (z=2) ----------------------
template <int K, int RELU, int STATS>
__global__ __launch_bounds__(256) void gemm_mfma2(const __hip_bfloat16* __restrict__ Aall,
                                                  const __hip_bfloat16* __restrict__ Btall,
                                                  const float* __restrict__ bias0,
                                                  const float* __restrict__ bias1,
                                                  float* __restrict__ Call,
                                                  float* __restrict__ csumB) {
  int z = blockIdx.z;
  const __hip_bfloat16* A = Aall + (size_t)z * NN * K;
  const __hip_bfloat16* Bt = Btall + (size_t)z * CC * K;
  const float* bias = z ? bias1 : bias0;
  float* csum = csumB ? csumB + z * 2 * CC : nullptr;
  float* csq = csum ? csum + CC : nullptr;
  int t = threadIdx.x;
  int lane = t & 63, wv = t >> 6;
  int l15 = lane & 15, lhi = lane >> 4;
  int row0 = blockIdx.x * 16;
  int col0 = wv * 64;
  const __hip_bfloat16* ap = A + (size_t)(row0 + l15) * K + lhi * 8;
  f32x4 acc[4] = {};
#pragma unroll
  for (int ks = 0; ks < K / 32; ks++) {
    bf16x8 a = *(const bf16x8*)(ap + ks * 32);
#pragma unroll
    for (int f = 0; f < 4; f++) {
      bf16x8 b = *(const bf16x8*)(Bt + (size_t)(col0 + f * 16 + l15) * K + ks * 32 + lhi * 8);
      acc[f] = __builtin_amdgcn_mfma_f32_16x16x32_bf16(a, b, acc[f], 0, 0, 0);
    }
  }
  float* C = Call + (size_t)z * NN * CC;
#pragma unroll
  for (int f = 0; f < 4; f++) {
    int col = col0 + f * 16 + l15;
    float bs = bias ? bias[col] : 0.f;
    float s = 0.f, q = 0.f;
#pragma unroll
    for (int reg = 0; reg < 4; reg++) {
      float v = acc[f][reg] + bs;
      if (RELU) v = fmaxf(v, 0.f);
      acc[f][reg] = v;
      if (STATS) {
        s += v;
        q += v * v;
      }
    }
    if (STATS) {
      s += __shfl_xor(s, 16, 64);
      s += __shfl_xor(s, 32, 64);
      q += __shfl_xor(q, 16, 64);
      q += __shfl_xor(q, 32, 64);
      if (lhi == 0) {
        atomicAdd(&csum[col], s);
        atomicAdd(&csq[col], q);
      }
    }
  }
#pragma unroll
  for (int reg = 0; reg < 4; reg++) {
    int row = row0 + lhi * 4 + reg;
#pragma unroll
    for (int f = 0; f < 4; f++)
      C[(size_t)row * CC + col0 + f * 16 + l15] = acc[f][reg];
  }
}

// ---- fused BN-apply (no relu) + row l2norm, both branches (z=2) -----------
__global__ __launch_bounds__(256) void bn_l2z(const float* __restrict__ Hall,
                                              const float* __restrict__ csumB,
                                              const float* __restrict__ g,
                                              const float* __restrict__ b,
                                              __hip_bfloat16* __restrict__ HbAll,
                                              __hip_bfloat16* __restrict__ hnbAll) {
  __shared__ float red[256];
  int z = blockIdx.z;
  const float* X = Hall + (size_t)z * NN * CC;
  const float* csum = csumB + z * 2 * CC;
  const float* csq = csum + CC;
  __hip_bfloat16* Hb = HbAll + (size_t)z * NN * CC;
  __hip_bfloat16* hnb = hnbAll + (size_t)z * NN * CC;
  int i = blockIdx.x, t = threadIdx.x;
  float m = csum[t] / (float)NN;
  float var = csq[t] / (float)NN - m * m;
  float istd = 1.0f / sqrtf(var + 1e-5f);
  float v = g[t] * (X[(size_t)i * CC + t] - m) * istd + b[t];
  Hb[(size_t)i * CC + t] = __float2bfloat16(v);
  red[t] = v * v;
  __syncthreads();
  for (int s = 128; s > 0; s >>= 1) {
    if (t < s) red[t] += red[t + s];
    __syncthreads();
  }
  hnb[(size_t)i * CC + t] = __float2bfloat16(v / (sqrtf(red[0]) + EPSF));
}

// ---------------- top-k positives, both branches (z=2) ---------------------
__global__ __launch_bounds__(256) void topk_groupz(const int* __restrict__ cntA,
                                                   const int* __restrict__ idxA,
                                                   const __hip_bfloat16* __restrict__ hnbAll,
                                                   int* __restrict__ posidxAll) {
  __shared__ int s_j[4][MAXD];
  __shared__ float s_sim[4][MAXD];
  int z = blockIdx.z;
  const __hip_bfloat16* hnb = hnbAll + (size_t)z * NN * CC;
  int* posidx = posidxAll + (size_t)z * NN * 5;
  int wv = threadIdx.x >> 6, lane = threadIdx.x & 63;
  int grp = lane >> 4, gl = lane & 15;
  int i = blockIdx.x * 4 + wv;
  int c = cntA[i];
  const bf16x8* qrow = (const bf16x8*)(hnb + (size_t)i * CC);
  bf16x8 qa = qrow[gl], qb = qrow[16 + gl];
  float q0[8], q1[8];
#pragma unroll
  for (int d = 0; d < 8; d++) {
    q0[d] = b2f(qa[d]);
    q1[d] = b2f(qb[d]);
  }
  for (int e = lane; e < c; e += 64) s_j[wv][e] = idxA[i * MAXD + e];
  __syncthreads();
  int passes = (c + 3) >> 2;
  for (int p = 0; p < passes; p++) {
    int e = p * 4 + grp;
    bool val = e < c;
    int j = val ? s_j[wv][e] : i;
    const bf16x8* hr = (const bf16x8*)(hnb + (size_t)j * CC);
    bf16x8 v0 = hr[gl];
    bf16x8 v1 = hr[16 + gl];
    float acc = 0.f;
#pragma unroll
    for (int d = 0; d < 8; d++) acc += q0[d] * b2f(v0[d]) + q1[d] * b2f(v1[d]);
#pragma unroll
    for (int m = 1; m <= 8; m <<= 1) acc += __shfl_xor(acc, m, 64);
    if (gl == 0 && val) s_sim[wv][e] = acc;
  }
  __syncthreads();
  float sim[2];
  int jj[2];
#pragma unroll
  for (int r = 0; r < 2; r++) {
    int e = lane + r * 64;
    bool v = e < c;
    sim[r] = v ? s_sim[wv][e] : -1e30f;
    jj[r] = v ? s_j[wv][e] : NN;
  }
  for (int k = 0; k < 5; k++) {
    float bv;
    int bj, br;
    if (sim[0] > sim[1] || (sim[0] == sim[1] && jj[0] < jj[1])) {
      bv = sim[0]; bj = jj[0]; br = 0;
    } else {
      bv = sim[1]; bj = jj[1]; br = 1;
    }
    float rv = bv;
    int rj = bj;
#pragma unroll
    for (int m = 1; m < 64; m <<= 1) {
      float ov = __shfl_xor(rv, m, 64);
      int oj = __shfl_xor(rj, m, 64);
      if (ov > rv || (ov == rv && oj < rj)) {
        rv = ov;
        rj = oj;
      }
    }
    if (lane == 0) posidx[i * 5 + k] = (rv > -1e29f) ? rj : -1;
    if (bj == rj && bv == rv && rv > -1e29f) {
      sim[br] = -1e30f;
      jj[br] = NN;
    }
  }
}

// ---- fused W2 gemm: BN(csumP)+relu on P1 fp32 inline -> MFMA -> l2norm ----
// Replaces bn_applyz + the bf16 W2 gemm: one dispatch, identical numerics.
__global__ __launch_bounds__(256) void gemm_w2_fused(
    const float* __restrict__ P1all, const float* __restrict__ csumP,
    const float* __restrict__ g0, const float* __restrict__ g1,
    const float* __restrict__ be0, const float* __restrict__ be1,
    const __hip_bfloat16* __restrict__ W2T,
    const float* __restrict__ b2h, const float* __restrict__ b2t,
    __hip_bfloat16* __restrict__ hpnAll) {
  __shared__ float rnorm[16];
  __shared__ float sm[CC], si[CC], sg[CC], sb[CC];
  int z = blockIdx.z;
  const float* X = P1all + (size_t)z * NN * CC;
  const float* csum = csumP + z * 2 * CC;
  const float* csq = csum + CC;
  const float* g = z ? g1 : g0;
  const float* be = z ? be1 : be0;
  const __hip_bfloat16* Bt = W2T + (size_t)z * CC * CC;
  const float* bias = z ? b2t : b2h;
  __hip_bfloat16* Cb = hpnAll + (size_t)z * NN * CC;
  int t = threadIdx.x;
  {
    float m = csum[t] / (float)NN;
    float var = csq[t] / (float)NN - m * m;
    sm[t] = m;
    si[t] = 1.0f / sqrtf(var + 1e-5f);
    sg[t] = g[t];
    sb[t] = be[t];
  }
  if (t < 16) rnorm[t] = 0.f;
  __syncthreads();
  int lane = t & 63, wv = t >> 6;
  int l15 = lane & 15, lhi = lane >> 4;
  int row0 = blockIdx.x * 16;
  int col0 = wv * 64;
  const float* ap = X + (size_t)(row0 + l15) * CC + lhi * 8;
  f32x4 acc[4] = {};
#pragma unroll
  for (int ks = 0; ks < CC / 32; ks++) {
    int k0 = ks * 32 + lhi * 8;
    float4 f0 = *(const float4*)(ap + ks * 32);
    float4 f1 = *(const float4*)(ap + ks * 32 + 4);
    float vv[8] = {f0.x, f0.y, f0.z, f0.w, f1.x, f1.y, f1.z, f1.w};
    bf16x8 a;
#pragma unroll
    for (int d = 0; d < 8; d++) {
      float v = sg[k0 + d] * (vv[d] - sm[k0 + d]) * si[k0 + d] + sb[k0 + d];
      a[d] = f2b(fmaxf(v, 0.f));
    }
#pragma unroll
    for (int f = 0; f < 4; f++) {
      bf16x8 b = *(const bf16x8*)(Bt + (size_t)(col0 + f * 16 + l15) * CC + ks * 32 + lhi * 8);
      acc[f] = __builtin_amdgcn_mfma_f32_16x16x32_bf16(a, b, acc[f], 0, 0, 0);
    }
  }
  float vout[4][4];
#pragma unroll
  for (int f = 0; f < 4; f++) {
    int col = col0 + f * 16 + l15;
    float bs = bias[col];
#pragma unroll
    for (int reg = 0; reg < 4; reg++) vout[f][reg] = acc[f][reg] + bs;
  }
#pragma unroll
  for (int reg = 0; reg < 4; reg++) {
    float p = 0.f;
#pragma unroll
    for (int f = 0; f < 4; f++) p += vout[f][reg] * vout[f][reg];
#pragma unroll
    for (int m = 1; m <= 8; m <<= 1) p += __shfl_xor(p, m, 64);
    if (l15 == 0) atomicAdd(&rnorm[lhi * 4 + reg], p);
  }
  __syncthreads();
#pragma unroll
  for (int reg = 0; reg < 4; reg++) {
    float inv = 1.0f / (sqrtf(rnorm[lhi * 4 + reg]) + EPSF);
    int row = row0 + lhi * 4 + reg;
#pragma unroll
    for (int f = 0; f < 4; f++)
      Cb[(size_t)row * CC + col0 + f * 16 + l15] = __float2bfloat16(vout[f][reg] * inv);
  }
}

// ---------------- fused contrast, global_load_lds-staged B -----------------
__global__ __launch_bounds__(256) void contrast_mfmaz(const __hip_bfloat16* __restrict__ zn,
                                                      const __hip_bfloat16* __restrict__ hpnAll,
                                                      const int* __restrict__ posidxAll,
                                                      float* __restrict__ part_rs,
                                                      float* __restrict__ part_pm) {
  __shared__ unsigned lmask[64 * (JCH / 32)];
  __shared__ float lds_rs[64], lds_pm[64];
  __shared__ unsigned char ldsB[64 * 512];
  int t = threadIdx.x;
  int br = blockIdx.z;
  const __hip_bfloat16* hpn = hpnAll + (size_t)br * NN * CC;
  const int* posidx = posidxAll + (size_t)br * NN * 5;
  int bi = blockIdx.y * 64;
  int bj0 = blockIdx.x * JCH;
  for (int w = t; w < 64 * (JCH / 32); w += 256) lmask[w] = 0;
  if (t < 64) {
    lds_rs[t] = 0.f;
    lds_pm[t] = 0.f;
  }
  __syncthreads();
  for (int p = t; p < 64 * 5; p += 256) {
    int gj = posidx[(bi + p / 5) * 5 + (p % 5)];
    int loc = gj - bj0;
    if (loc >= 0 && loc < JCH)
      atomicOr(&lmask[(p / 5) * (JCH / 32) + (loc >> 5)], 1u << (loc & 31));
  }
  if (t < 64) {
    int loc = bi + t - bj0;
    if (loc >= 0 && loc < JCH)
      atomicOr(&lmask[t * (JCH / 32) + (loc >> 5)], 1u << (loc & 31));
  }
  int lane = t & 63, wv = t >> 6;
  int wi = wv >> 1, wj = wv & 1;
  int l15 = lane & 15, lhi = lane >> 4;
  bf16x8 afrag[2][8];
#pragma unroll
  for (int fi = 0; fi < 2; fi++) {
    const __hip_bfloat16* ap = zn + (size_t)(bi + wi * 32 + fi * 16 + l15) * CC + lhi * 8;
#pragma unroll
    for (int ks = 0; ks < 8; ks++) afrag[fi][ks] = *(const bf16x8*)(ap + ks * 32);
  }
  float rs_acc[2][4] = {}, pm_acc[2][4] = {};
  int rb0 = wj * 32 + l15;
  int rb1 = rb0 + 16;
  int sw = rb0 & 7;
  int row_l = lane >> 5;
  int c16p = lane & 31;
  __syncthreads();
  for (int jt = 0; jt < JCH / 64; jt++) {
    __syncthreads();
#pragma unroll
    for (int it = 0; it < 8; it++) {
      int r = wv * 16 + it * 2 + row_l;
      const __hip_bfloat16* src =
          hpn + (size_t)(bj0 + jt * 64 + r) * CC + ((c16p ^ (r & 7)) << 3);
      __builtin_amdgcn_global_load_lds(
          (const __attribute__((address_space(1))) void*)src,
          (__attribute__((address_space(3))) void*)(ldsB + wv * 8192 + it * 1024),
          16, 0, 0);
    }
    __syncthreads();
    f32x4 acc[2][2] = {};
#pragma unroll
    for (int ks = 0; ks < 8; ks++) {
      int s16 = (ks << 2) + lhi;
      bf16x8 b0 = *(const bf16x8*)(ldsB + rb0 * 512 + ((s16 ^ sw) << 4));
      bf16x8 b1 = *(const bf16x8*)(ldsB + rb1 * 512 + ((s16 ^ sw) << 4));
      acc[0][0] = __builtin_amdgcn_mfma_f32_16x16x32_bf16(afrag[0][ks], b0, acc[0][0], 0, 0, 0);
      acc[1][0] = __builtin_amdgcn_mfma_f32_16x16x32_bf16(afrag[1][ks], b0, acc[1][0], 0, 0, 0);
      acc[0][1] = __builtin_amdgcn_mfma_f32_16x16x32_bf16(afrag[0][ks], b1, acc[0][1], 0, 0, 0);
      acc[1][1] = __builtin_amdgcn_mfma_f32_16x16x32_bf16(afrag[1][ks], b1, acc[1][1], 0, 0, 0);
    }
#pragma unroll
    for (int fi = 0; fi < 2; fi++) {
#pragma unroll
      for (int reg = 0; reg < 4; reg++) {
        int rloc = wi * 32 + fi * 16 + lhi * 4 + reg;
        unsigned word = lmask[rloc * (JCH / 32) + jt * 2 + wj];
#pragma unroll
        for (int fj = 0; fj < 2; fj++) {
          float e = __expf(acc[fi][fj][reg] * TAU_INV);
          rs_acc[fi][reg] += e;
          if ((word >> (fj * 16 + l15)) & 1) pm_acc[fi][reg] += e;
        }
      }
    }
  }
#pragma unroll
  for (int fi = 0; fi < 2; fi++) {
#pragma unroll
    for (int reg = 0; reg < 4; reg++) {
      float rs = rs_acc[fi][reg], pm = pm_acc[fi][reg];
#pragma unroll
      for (int m = 8; m >= 1; m >>= 1) {
        rs += __shfl_xor(rs, m, 64);
        pm += __shfl_xor(pm, m, 64);
      }
      if (l15 == 0) {
        int rloc = wi * 32 + fi * 16 + lhi * 4 + reg;
        atomicAdd(&lds_rs[rloc], rs);
        atomicAdd(&lds_pm[rloc], pm);
      }
    }
  }
  __syncthreads();
  if (t < 64) {
    size_t po = ((size_t)br * NCH + blockIdx.x) * NN + bi + t;
    part_rs[po] = lds_rs[t];
    part_pm[po] = lds_pm[t];
  }
}

// ---------------- final loss over both branches' chunk partials ------------
__global__ __launch_bounds__(256) void loss_reduce3(const float* __restrict__ part_rs,
                                                    const float* __restrict__ part_pm,
                                                    float* __restrict__ out) {
  __shared__ float red[256];
  int t = threadIdx.x;
  float s = 0.f;
  for (int i = blockIdx.x * 256 + t; i < NN; i += gridDim.x * 256) {
#pragma unroll
    for (int b = 0; b < 2; b++) {
      float rs = 0.f, pm = 0.f;
#pragma unroll
      for (int c = 0; c < NCH; c++) {
        rs += part_rs[((size_t)b * NCH + c) * NN + i];
        pm += part_pm[((size_t)b * NCH + c) * NN + i];
      }
      float sn = pm / (rs + EPSF);
      s += -logf(sn + EPSF);
    }
  }
  red[t] = s;
  __syncthreads();
  for (int k = 128; k > 0; k >>= 1) {
    if (t < k) red[t] += red[t + k];
    __syncthreads();
  }
  if (t == 0) atomicAdd(out, red[0] / (float)NN);
}

extern "C" void kernel_launch(void* const* d_in, const int* in_sizes, int n_in,
                              void* d_out, int out_size, void* d_ws, size_t ws_size,
                              hipStream_t stream) {
  const float* x = (const float*)d_in[0];
  const float* z1 = (const float*)d_in[1];
  const float* adj = (const float*)d_in[2];
  const float* adj2 = (const float*)d_in[3];
  const float* W_gcn = (const float*)d_in[4];
  const float* W_het = (const float*)d_in[5];
  const float* hpW1 = (const float*)d_in[6];
  const float* hpb1 = (const float*)d_in[7];
  const float* hpg = (const float*)d_in[8];
  const float* hpbe = (const float*)d_in[9];
  const float* hpW2 = (const float*)d_in[10];
  const float* hpb2 = (const float*)d_in[11];
  const float* tpW1 = (const float*)d_in[12];
  const float* tpb1 = (const float*)d_in[13];
  const float* tpg = (const float*)d_in[14];
  const float* tpbe = (const float*)d_in[15];
  const float* tpW2 = (const float*)d_in[16];
  const float* tpb2 = (const float*)d_in[17];
  const float* bng = (const float*)d_in[18];
  const float* bnb = (const float*)d_in[19];
  float* out = (float*)d_out;

  float* ws = (float*)d_ws;
  size_t oZN   = 0;
  size_t oX16  = oZN + (size_t)NN * CC / 2;
  size_t oB1B  = oX16 + (size_t)NN * FF / 2;
  size_t oB2B  = oB1B + (size_t)NN * FF;
  size_t oH    = oB2B + (size_t)NN * FF;
  size_t oHB   = oH + (size_t)2 * NN * CC;
  size_t oHNB  = oHB + (size_t)NN * CC;
  size_t oP1   = oHNB + (size_t)NN * CC;
  size_t oPN   = oP1 + (size_t)2 * NN * CC;
  size_t oIDX  = oPN + (size_t)NN * CC;
  size_t oCNT  = oIDX + (size_t)2 * NN * MAXD;
  size_t oDI   = oCNT + 2 * NN;
  size_t oCS   = oDI + 2 * NN;
  size_t oPI   = oCS + 8 * CC;
  size_t oPR   = oPI + 2 * NN * 5;
  size_t oPP   = oPR + (size_t)2 * NCH * NN;
  size_t oWT   = oPP + (size_t)2 * NCH * NN;
  size_t oW1T  = oWT + (size_t)CC * FF;
  size_t oW2T  = oW1T + (size_t)CC * CC;

  __hip_bfloat16* zn16 = (__hip_bfloat16*)(ws + oZN);
  __hip_bfloat162* x16 = (__hip_bfloat162*)(ws + oX16);
  __hip_bfloat162* buf1b = (__hip_bfloat162*)(ws + oB1B);
  __hip_bfloat162* buf2b = (__hip_bfloat162*)(ws + oB2B);
  float* Hall = ws + oH;
  __hip_bfloat16* HbAll = (__hip_bfloat16*)(ws + oHB);
  __hip_bfloat16* hnbAll = (__hip_bfloat16*)(ws + oHNB);
  float* P1all = ws + oP1;
  __hip_bfloat16* hpnAll = (__hip_bfloat16*)(ws + oPN);
  int* idxAll = (int*)(ws + oIDX);
  int* cntAll = (int*)(ws + oCNT);
  float* dinvAll = ws + oDI;
  float* csumH = ws + oCS;            // [2][2*CC]
  float* csumP = csumH + 4 * CC;      // [2][2*CC]
  int* posidxAll = (int*)(ws + oPI);
  float* part_rs = ws + oPR;
  float* part_pm = ws + oPP;
  __hip_bfloat16* WT = (__hip_bfloat16*)(ws + oWT);
  __hip_bfloat16* W1T = (__hip_bfloat16*)(ws + oW1T);
  __hip_bfloat16* W2T = (__hip_bfloat16*)(ws + oW2T);

  preamble<<<NB_BUILD + NB_L2N + NB_CAST + NB_WT + 1, 256, 0, stream>>>(
      adj, adj2, cntAll, idxAll, dinvAll, z1, zn16, x, (__hip_bfloat16*)x16,
      W_gcn, W_het, hpW1, tpW1, hpW2, tpW2, WT, W1T, W2T, csumH, out);

  spmm_b16z<<<dim3(NN, 1, 2), 256, 0, stream>>>(cntAll, idxAll, dinvAll, x16, 0, buf1b);
  spmm_b16z<<<dim3(NN, 1, 2), 256, 0, stream>>>(cntAll, idxAll, dinvAll, buf1b,
                                                (size_t)NN * FF / 2, buf2b);
  gemm_mfma2<FF, 1, 1><<<dim3(NN / 16, 1, 2), 256, 0, stream>>>(
      (const __hip_bfloat16*)buf2b, WT, nullptr, nullptr, Hall, csumH);
  bn_l2z<<<dim3(NN, 1, 2), 256, 0, stream>>>(Hall, csumH, bng, bnb, HbAll, hnbAll);
  topk_groupz<<<dim3(NN / 4, 1, 2), 256, 0, stream>>>(cntAll, idxAll, hnbAll, posidxAll);
  gemm_mfma2<CC, 0, 1><<<dim3(NN / 16, 1, 2), 256, 0, stream>>>(
      HbAll, W1T, hpb1, tpb1, P1all, csumP);
  gemm_w2_fused<<<dim3(NN / 16, 1, 2), 256, 0, stream>>>(
      P1all, csumP, hpg, tpg, hpbe, tpbe, W2T, hpb2, tpb2, hpnAll);
  contrast_mfmaz<<<dim3(NCH, NN / 64, 2), 256, 0, stream>>>(zn16, hpnAll, posidxAll,
                                                            part_rs, part_pm);
  loss_reduce3<<<16, 256, 0, stream>>>(part_rs, part_pm, out);
  (void)in_sizes; (void)n_in; (void)out_size; (void)ws_size;
}